// Round 9
// baseline (353.126 us; speedup 1.0000x reference)
//
#include <hip/hip_runtime.h>
#include <hip/hip_cooperative_groups.h>
#include <hip/hip_bf16.h>

namespace cg = cooperative_groups;

#define NODES_DIM 64   // H*D = 4*16
#define SL_DIM    12   // H*DC = 4*3
#define CAP       64   // bucket capacity; deg ~ Poisson(16), P(>=64) ~ 1e-18

// round-to-nearest-even fp32 -> bf16
__device__ __forceinline__ unsigned short f2bf(float f) {
    union { float f; unsigned u; } x; x.f = f;
    const unsigned r = x.u + 0x7FFFu + ((x.u >> 16) & 1u);
    return (unsigned short)(r >> 16);
}

// ---------------------------------------------------------------------------
// Cooperative mega-kernel. One dispatch replaces memset+qkv_fill+node:
//  phase 0: zero cursor (grid-strided)            -> grid.sync()
//  phase 1: parity roles (R7-proven bodies):
//           even blocks: QKV, 32 rows/iter, W staged ONCE per block.
//             Wq fp32 in LDS (16 KB); Wk/Wv bf16-packed pairs (8+8 KB).
//           odd blocks: bucket fill, 1024 edges/iter, 4 stride-256
//             edges/thread, int list entries.     -> grid.sync()
//  phase 2: node phase (R6/R7 edge-quad body), grid-strided, 4 nodes/block.
// LDS 32 KB -> 5 blocks/CU -> 20 waves/CU in all phases.
// ---------------------------------------------------------------------------
__global__ __launch_bounds__(256) void mega_kernel(
    const float* __restrict__ h,
    const float* __restrict__ Wq, const float* __restrict__ bq,
    const float* __restrict__ Wk, const float* __restrict__ bk,
    const float* __restrict__ Wv, const float* __restrict__ bv,
    const float* __restrict__ s_l,
    const int* __restrict__ src, const int* __restrict__ dst,
    float* __restrict__ Q, unsigned* __restrict__ KV,
    int* __restrict__ cursor, int* __restrict__ list,
    float* __restrict__ out,
    int N, int E, int ngroupsQ, int nchunks, int nodeGroups)
{
    cg::grid_group grid = cg::this_grid();

    __shared__ float    sWq[64][64];   // 16 KB fp32
    __shared__ unsigned sWk[32][64];   //  8 KB bf16-pair (k even low, k odd high)
    __shared__ unsigned sWv[32][64];   //  8 KB

    // ---------------- phase 0: zero cursor ----------------
    {
        const int stride = gridDim.x * 256;
        for (int i = blockIdx.x * 256 + threadIdx.x; i < N; i += stride)
            cursor[i] = 0;
    }
    grid.sync();

    // ---------------- phase 1: qkv / fill by parity ----------------
    const int half = gridDim.x >> 1;
    if ((blockIdx.x & 1) == 0) {
        // ------- qkv role -------
        for (int i = threadIdx.x; i < 64 * 64; i += 256)
            sWq[i >> 6][i & 63] = Wq[i];
        for (int i = threadIdx.x; i < 32 * 64; i += 256) {
            const int k2 = i >> 6, cc = i & 63;
            sWk[k2][cc] = (unsigned)f2bf(Wk[(2 * k2) * 64 + cc])
                        | ((unsigned)f2bf(Wk[(2 * k2 + 1) * 64 + cc]) << 16);
            sWv[k2][cc] = (unsigned)f2bf(Wv[(2 * k2) * 64 + cc])
                        | ((unsigned)f2bf(Wv[(2 * k2 + 1) * 64 + cc]) << 16);
        }
        __syncthreads();

        const int c    = threadIdx.x & 63;
        const int slot = __builtin_amdgcn_readfirstlane((int)(threadIdx.x >> 6));
        const float bqc = bq[c], bkc = bk[c], bvc = bv[c];

        for (int gq = blockIdx.x >> 1; gq < ngroupsQ; gq += half) {
            const int rowBase = gq * 32 + slot * 8;
            if (rowBase >= N) continue;
            const int nrows = (N - rowBase < 8) ? (N - rowBase) : 8;

            float acc0[8], acc1[8], acc2[8];
#pragma unroll
            for (int r = 0; r < 8; ++r) { acc0[r] = 0.f; acc1[r] = 0.f; acc2[r] = 0.f; }

            if (nrows == 8) {
                for (int k4 = 0; k4 < 16; ++k4) {
                    float4 hv[8];
#pragma unroll
                    for (int r = 0; r < 8; ++r)
                        hv[r] = ((const float4*)(h + (size_t)(rowBase + r) * 64))[k4];
                    const unsigned pk0 = sWk[2 * k4][c],     pv0 = sWv[2 * k4][c];
                    const unsigned pk1 = sWk[2 * k4 + 1][c], pv1 = sWv[2 * k4 + 1][c];
                    const float wkx[4] = {
                        __uint_as_float(pk0 << 16), __uint_as_float(pk0 & 0xFFFF0000u),
                        __uint_as_float(pk1 << 16), __uint_as_float(pk1 & 0xFFFF0000u) };
                    const float wvx[4] = {
                        __uint_as_float(pv0 << 16), __uint_as_float(pv0 & 0xFFFF0000u),
                        __uint_as_float(pv1 << 16), __uint_as_float(pv1 & 0xFFFF0000u) };
#pragma unroll
                    for (int kk = 0; kk < 4; ++kk) {
                        const int k = k4 * 4 + kk;
                        const float wq = sWq[k][c];
#pragma unroll
                        for (int r = 0; r < 8; ++r) {
                            const float hh = (&hv[r].x)[kk];
                            acc0[r] += hh * wq;
                            acc1[r] += hh * wkx[kk];
                            acc2[r] += hh * wvx[kk];
                        }
                    }
                }
            } else {
                for (int k4 = 0; k4 < 16; ++k4) {
                    float4 hv[8];
#pragma unroll
                    for (int r = 0; r < 8; ++r)
                        hv[r] = (r < nrows)
                            ? ((const float4*)(h + (size_t)(rowBase + r) * 64))[k4]
                            : make_float4(0.f, 0.f, 0.f, 0.f);
                    const unsigned pk0 = sWk[2 * k4][c],     pv0 = sWv[2 * k4][c];
                    const unsigned pk1 = sWk[2 * k4 + 1][c], pv1 = sWv[2 * k4 + 1][c];
                    const float wkx[4] = {
                        __uint_as_float(pk0 << 16), __uint_as_float(pk0 & 0xFFFF0000u),
                        __uint_as_float(pk1 << 16), __uint_as_float(pk1 & 0xFFFF0000u) };
                    const float wvx[4] = {
                        __uint_as_float(pv0 << 16), __uint_as_float(pv0 & 0xFFFF0000u),
                        __uint_as_float(pv1 << 16), __uint_as_float(pv1 & 0xFFFF0000u) };
#pragma unroll
                    for (int kk = 0; kk < 4; ++kk) {
                        const int k = k4 * 4 + kk;
                        const float wq = sWq[k][c];
#pragma unroll
                        for (int r = 0; r < 8; ++r) {
                            const float hh = (&hv[r].x)[kk];
                            acc0[r] += hh * wq;
                            acc1[r] += hh * wkx[kk];
                            acc2[r] += hh * wvx[kk];
                        }
                    }
                }
            }

#pragma unroll
            for (int r = 0; r < 8; ++r) {
                if (r < nrows) {
                    const size_t o = (size_t)(rowBase + r) * 64 + c;
                    Q[o] = acc0[r] + bqc;
                    const unsigned short kb = f2bf(acc1[r] + bkc);
                    const unsigned short vb = f2bf(acc2[r] + bvc);
                    KV[o] = ((unsigned)vb << 16) | (unsigned)kb;
                }
            }
        }
    } else {
        // ------- fill role -------
        for (int ch = blockIdx.x >> 1; ch < nchunks; ch += half) {
            const int base = ch * 1024 + (int)threadIdx.x;
            int sv[4], dv[4];
            bool ok[4];
#pragma unroll
            for (int j = 0; j < 4; ++j) {
                const int e = base + j * 256;
                ok[j] = e < E;
                sv[j] = ok[j] ? src[e] : 0;
                dv[j] = ok[j] ? dst[e] : 0;
            }
#pragma unroll
            for (int j = 0; j < 4; ++j) {
                if (ok[j]) {
                    const int pos = atomicAdd(&cursor[dv[j]], 1);
                    if (pos < CAP) list[((size_t)dv[j] << 6) + pos] = sv[j];
                }
            }
        }
    }
    grid.sync();

    // ---------------- phase 2: node (edge-quad layout) ----------------
    const int lane = threadIdx.x & 63;
    const int e2   = lane >> 4;
    const int hq   = lane & 15;
    const int head = hq >> 2;
    const int quad = hq & 3;
    const int wslot = threadIdx.x >> 6;

    for (int g = blockIdx.x; g < nodeGroups; g += gridDim.x) {
        const int node = g * 4 + wslot;
        if (node >= N) continue;

        int deg = cursor[node];
        deg = (deg > CAP) ? CAP : deg;

        const float4 qv = *(const float4*)(Q + (size_t)node * 64 + (hq << 2));
        const float slv = (quad < 3) ? s_l[(size_t)node * SL_DIM + head * 3 + quad] : 0.f;
        const int* lbase = list + ((size_t)node << 6);

        float4 accV = make_float4(0.f, 0.f, 0.f, 0.f);
        float zs = 0.f;

        const int ng = (deg + 3) >> 2;
#pragma unroll 2
        for (int i = 0; i < ng; ++i) {
            const int slot  = (i << 2) + e2;
            const bool valid = slot < deg;
            const int sidx  = lbase[valid ? slot : 0];

            const uint4 kv = *(const uint4*)(KV + (size_t)sidx * 64 + (hq << 2));
            const float a  = (quad < 3) ? s_l[(size_t)sidx * SL_DIM + head * 3 + quad] : 0.f;

            float dt = __uint_as_float(kv.x << 16) * qv.x
                     + __uint_as_float(kv.y << 16) * qv.y
                     + __uint_as_float(kv.z << 16) * qv.z
                     + __uint_as_float(kv.w << 16) * qv.w;
            const float df = a - slv;
            float ds = df * df;

            dt += __shfl_xor(dt, 1, 4);
            dt += __shfl_xor(dt, 2, 4);
            ds += __shfl_xor(ds, 1, 4);
            ds += __shfl_xor(ds, 2, 4);

            const float sc = fminf(fmaxf(dt * 0.25f, -5.f), 5.f);
            float score = __expf(sc);
            score = valid ? score : 0.f;
            const float w    = __expf(-ds * ds);
            const float news = score * w;
            zs += score;

            accV.x += __uint_as_float(kv.x & 0xFFFF0000u) * news;
            accV.y += __uint_as_float(kv.y & 0xFFFF0000u) * news;
            accV.z += __uint_as_float(kv.z & 0xFFFF0000u) * news;
            accV.w += __uint_as_float(kv.w & 0xFFFF0000u) * news;
        }

#pragma unroll
        for (int m = 16; m <= 32; m <<= 1) {
            accV.x += __shfl_xor(accV.x, m);
            accV.y += __shfl_xor(accV.y, m);
            accV.z += __shfl_xor(accV.z, m);
            accV.w += __shfl_xor(accV.w, m);
            zs     += __shfl_xor(zs, m);
        }

        if (e2 == 0) {
            const float inv = (zs > 0.f) ? (1.f / zs) : 1.f;
            float4 o;
            o.x = accV.x * inv; o.y = accV.y * inv;
            o.z = accV.z * inv; o.w = accV.w * inv;
            *(float4*)(out + (size_t)node * 64 + (hq << 2)) = o;
        }
    }
}

extern "C" void kernel_launch(void* const* d_in, const int* in_sizes, int n_in,
                              void* d_out, int out_size, void* d_ws, size_t ws_size,
                              hipStream_t stream) {
    const float* h   = (const float*)d_in[0];
    const float* s_l = (const float*)d_in[1];
    const float* Wq  = (const float*)d_in[2];
    const float* bq  = (const float*)d_in[3];
    const float* Wk  = (const float*)d_in[4];
    const float* bk  = (const float*)d_in[5];
    const float* Wv  = (const float*)d_in[6];
    const float* bv  = (const float*)d_in[7];
    const int*   src = (const int*)d_in[8];
    const int*   dst = (const int*)d_in[9];
    float* out = (float*)d_out;

    int N = in_sizes[0] / 64;   // 50000
    int E = in_sizes[8];        // 800000

    // workspace: Q fp32 (N*64) | KV packed (N*64) | cursor (N int) | list int (N*64)
    float*    Q      = (float*)d_ws;
    unsigned* KV     = (unsigned*)(Q + (size_t)N * NODES_DIM);
    int*      cursor = (int*)(KV + (size_t)N * NODES_DIM);
    int*      list   = cursor + N;

    // grid = co-resident capacity (cooperative requirement), even for parity
    int perCU = 0;
    hipOccupancyMaxActiveBlocksPerMultiprocessor(&perCU, mega_kernel, 256, 0);
    if (perCU < 1) perCU = 1;
    int numCU = 256;
    {
        hipDeviceProp_t prop;
        int dev = 0;
        if (hipGetDevice(&dev) == hipSuccess &&
            hipGetDeviceProperties(&prop, dev) == hipSuccess)
            numCU = prop.multiProcessorCount;
    }
    int gridBlocks = perCU * numCU;
    if (gridBlocks < 2) gridBlocks = 2;
    gridBlocks &= ~1;

    int ngroupsQ   = (N + 31) / 32;     // 1563
    int nchunks    = (E + 1023) / 1024; // 782
    int nodeGroups = (N + 3) / 4;       // 12500

    void* args[] = {
        (void*)&h, (void*)&Wq, (void*)&bq, (void*)&Wk, (void*)&bk,
        (void*)&Wv, (void*)&bv, (void*)&s_l, (void*)&src, (void*)&dst,
        (void*)&Q, (void*)&KV, (void*)&cursor, (void*)&list, (void*)&out,
        (void*)&N, (void*)&E, (void*)&ngroupsQ, (void*)&nchunks, (void*)&nodeGroups
    };
    hipLaunchCooperativeKernel((const void*)mega_kernel,
                               dim3(gridBlocks), dim3(256),
                               args, 0, stream);
}

// Round 10
// 176.975 us; speedup vs baseline: 1.9953x; 1.9953x over previous
//
#include <hip/hip_runtime.h>
#include <hip/hip_bf16.h>

#define NODES_DIM 64   // H*D = 4*16
#define SL_DIM    12   // H*DC = 4*3
#define CAP       64   // bucket capacity; deg ~ Poisson(16), P(>=64) ~ 1e-18

// round-to-nearest-even fp32 -> bf16
__device__ __forceinline__ unsigned short f2bf(float f) {
    union { float f; unsigned u; } x; x.f = f;
    const unsigned r = x.u + 0x7FFFu + ((x.u >> 16) & 1u);
    return (unsigned short)(r >> 16);
}

// ---------------------------------------------------------------------------
// Fused kernel: heterogeneous grid, role = blockIdx%3 (2 qkv : 1 fill).
//  qkv role: 32 rows/block, 8 rows/slot. LDS 32 KB: Wq fp32 (16 KB),
//            Wk/Wv bf16-packed pairs (8+8 KB) -> 5 blocks/CU (vs 3 at 48 KB).
//            h loads wave-uniform -> scalar. Q fp32; K,V packed bf16.
//  fill role: 1024 edges/block, 4 stride-256 edges/thread, 4 independent
//            atomic+store chains, int list entries.
// Disjoint pipes + no data dependence -> co-residency overlaps at ~max().
// ---------------------------------------------------------------------------
__global__ __launch_bounds__(256) void qkv_fill_kernel(
    const float* __restrict__ h,
    const float* __restrict__ Wq, const float* __restrict__ bq,
    const float* __restrict__ Wk, const float* __restrict__ bk,
    const float* __restrict__ Wv, const float* __restrict__ bv,
    float* __restrict__ Q, unsigned* __restrict__ KV, int N,
    const int* __restrict__ src, const int* __restrict__ dst,
    int* __restrict__ cursor, int* __restrict__ list, int E)
{
    __shared__ float    sWq[64][64];   // 16 KB fp32
    __shared__ unsigned sWk[32][64];   //  8 KB bf16 pairs (k even low, k odd high)
    __shared__ unsigned sWv[32][64];   //  8 KB

    const int r = blockIdx.x % 3;
    const int g = blockIdx.x / 3;

    if (r == 2) {
        // ---------------- fill role ----------------
        const int e0 = g * 1024 + (int)threadIdx.x;
        int sv[4], dv[4];
        bool ok[4];
#pragma unroll
        for (int j = 0; j < 4; ++j) {
            const int e = e0 + j * 256;
            ok[j] = e < E;
            sv[j] = ok[j] ? src[e] : 0;
            dv[j] = ok[j] ? dst[e] : 0;
        }
#pragma unroll
        for (int j = 0; j < 4; ++j) {
            if (ok[j]) {
                const int pos = atomicAdd(&cursor[dv[j]], 1);
                if (pos < CAP) list[((size_t)dv[j] << 6) + pos] = sv[j];
            }
        }
        return;
    }

    // ---------------- qkv role ----------------
    const int qb = g * 2 + r;
    const int rowBase0 = qb * 32;
    if (rowBase0 >= N) return;

    for (int i = threadIdx.x; i < 64 * 64; i += 256)
        sWq[i >> 6][i & 63] = Wq[i];
    for (int i = threadIdx.x; i < 32 * 64; i += 256) {
        const int k2 = i >> 6, cc = i & 63;
        sWk[k2][cc] = (unsigned)f2bf(Wk[(2 * k2) * 64 + cc])
                    | ((unsigned)f2bf(Wk[(2 * k2 + 1) * 64 + cc]) << 16);
        sWv[k2][cc] = (unsigned)f2bf(Wv[(2 * k2) * 64 + cc])
                    | ((unsigned)f2bf(Wv[(2 * k2 + 1) * 64 + cc]) << 16);
    }
    __syncthreads();

    const int c    = threadIdx.x & 63;
    const int slot = __builtin_amdgcn_readfirstlane((int)(threadIdx.x >> 6));
    const int rowBase = rowBase0 + slot * 8;
    if (rowBase >= N) return;
    const int nrows = (N - rowBase < 8) ? (N - rowBase) : 8;

    float acc0[8], acc1[8], acc2[8];
#pragma unroll
    for (int rr = 0; rr < 8; ++rr) { acc0[rr] = 0.f; acc1[rr] = 0.f; acc2[rr] = 0.f; }

    if (nrows == 8) {
        for (int k4 = 0; k4 < 16; ++k4) {
            float4 hv[8];
#pragma unroll
            for (int rr = 0; rr < 8; ++rr)
                hv[rr] = ((const float4*)(h + (size_t)(rowBase + rr) * 64))[k4];
            const unsigned pk0 = sWk[2 * k4][c],     pv0 = sWv[2 * k4][c];
            const unsigned pk1 = sWk[2 * k4 + 1][c], pv1 = sWv[2 * k4 + 1][c];
            const float wkx[4] = {
                __uint_as_float(pk0 << 16), __uint_as_float(pk0 & 0xFFFF0000u),
                __uint_as_float(pk1 << 16), __uint_as_float(pk1 & 0xFFFF0000u) };
            const float wvx[4] = {
                __uint_as_float(pv0 << 16), __uint_as_float(pv0 & 0xFFFF0000u),
                __uint_as_float(pv1 << 16), __uint_as_float(pv1 & 0xFFFF0000u) };
#pragma unroll
            for (int kk = 0; kk < 4; ++kk) {
                const int k = k4 * 4 + kk;
                const float wq = sWq[k][c];
#pragma unroll
                for (int rr = 0; rr < 8; ++rr) {
                    const float hh = (&hv[rr].x)[kk];
                    acc0[rr] += hh * wq;
                    acc1[rr] += hh * wkx[kk];
                    acc2[rr] += hh * wvx[kk];
                }
            }
        }
    } else {
        for (int k4 = 0; k4 < 16; ++k4) {
            float4 hv[8];
#pragma unroll
            for (int rr = 0; rr < 8; ++rr)
                hv[rr] = (rr < nrows)
                    ? ((const float4*)(h + (size_t)(rowBase + rr) * 64))[k4]
                    : make_float4(0.f, 0.f, 0.f, 0.f);
            const unsigned pk0 = sWk[2 * k4][c],     pv0 = sWv[2 * k4][c];
            const unsigned pk1 = sWk[2 * k4 + 1][c], pv1 = sWv[2 * k4 + 1][c];
            const float wkx[4] = {
                __uint_as_float(pk0 << 16), __uint_as_float(pk0 & 0xFFFF0000u),
                __uint_as_float(pk1 << 16), __uint_as_float(pk1 & 0xFFFF0000u) };
            const float wvx[4] = {
                __uint_as_float(pv0 << 16), __uint_as_float(pv0 & 0xFFFF0000u),
                __uint_as_float(pv1 << 16), __uint_as_float(pv1 & 0xFFFF0000u) };
#pragma unroll
            for (int kk = 0; kk < 4; ++kk) {
                const int k = k4 * 4 + kk;
                const float wq = sWq[k][c];
#pragma unroll
                for (int rr = 0; rr < 8; ++rr) {
                    const float hh = (&hv[rr].x)[kk];
                    acc0[rr] += hh * wq;
                    acc1[rr] += hh * wkx[kk];
                    acc2[rr] += hh * wvx[kk];
                }
            }
        }
    }

    const float bqc = bq[c], bkc = bk[c], bvc = bv[c];
#pragma unroll
    for (int rr = 0; rr < 8; ++rr) {
        if (rr < nrows) {
            const size_t o = (size_t)(rowBase + rr) * 64 + c;
            Q[o] = acc0[rr] + bqc;
            const unsigned short kb = f2bf(acc1[rr] + bkc);
            const unsigned short vb = f2bf(acc2[rr] + bvc);
            KV[o] = ((unsigned)vb << 16) | (unsigned)kb;
        }
    }
}

// ---------------------------------------------------------------------------
// Node phase, edge-quad layout (R6-proven). One wave per node.
// lane = e2*16 + head*4 + quad. Per 4-edge group: 1 dwordx4 KV load/lane,
// width-4 2-stage shfl reduce, exp amortized, V accumulated in-lane.
// ---------------------------------------------------------------------------
__global__ __launch_bounds__(256) void node_kernel(
    const float* __restrict__ Q, const unsigned* __restrict__ KV,
    const float* __restrict__ s_l,
    const int* __restrict__ cursor, const int* __restrict__ list,
    float* __restrict__ out, int N)
{
    const int t = blockIdx.x * 256 + threadIdx.x;
    const int node = t >> 6;
    if (node >= N) return;
    const int lane = threadIdx.x & 63;
    const int e2   = lane >> 4;
    const int hq   = lane & 15;
    const int head = hq >> 2;
    const int quad = hq & 3;

    int deg = cursor[node];
    deg = (deg > CAP) ? CAP : deg;

    const float4 qv = *(const float4*)(Q + (size_t)node * 64 + (hq << 2));
    const float slv = (quad < 3) ? s_l[(size_t)node * SL_DIM + head * 3 + quad] : 0.f;

    const int* lbase = list + ((size_t)node << 6);

    float4 accV = make_float4(0.f, 0.f, 0.f, 0.f);
    float zs = 0.f;

    const int ng = (deg + 3) >> 2;
#pragma unroll 2
    for (int i = 0; i < ng; ++i) {
        const int slot  = (i << 2) + e2;
        const bool valid = slot < deg;
        const int sidx  = lbase[valid ? slot : 0];

        const uint4 kv = *(const uint4*)(KV + (size_t)sidx * 64 + (hq << 2));
        const float a  = (quad < 3) ? s_l[(size_t)sidx * SL_DIM + head * 3 + quad] : 0.f;

        float dt = __uint_as_float(kv.x << 16) * qv.x
                 + __uint_as_float(kv.y << 16) * qv.y
                 + __uint_as_float(kv.z << 16) * qv.z
                 + __uint_as_float(kv.w << 16) * qv.w;
        const float df = a - slv;
        float ds = df * df;

        dt += __shfl_xor(dt, 1, 4);
        dt += __shfl_xor(dt, 2, 4);
        ds += __shfl_xor(ds, 1, 4);
        ds += __shfl_xor(ds, 2, 4);

        const float sc = fminf(fmaxf(dt * 0.25f, -5.f), 5.f);
        float score = __expf(sc);
        score = valid ? score : 0.f;
        const float w    = __expf(-ds * ds);
        const float news = score * w;
        zs += score;

        accV.x += __uint_as_float(kv.x & 0xFFFF0000u) * news;
        accV.y += __uint_as_float(kv.y & 0xFFFF0000u) * news;
        accV.z += __uint_as_float(kv.z & 0xFFFF0000u) * news;
        accV.w += __uint_as_float(kv.w & 0xFFFF0000u) * news;
    }

#pragma unroll
    for (int m = 16; m <= 32; m <<= 1) {
        accV.x += __shfl_xor(accV.x, m);
        accV.y += __shfl_xor(accV.y, m);
        accV.z += __shfl_xor(accV.z, m);
        accV.w += __shfl_xor(accV.w, m);
        zs     += __shfl_xor(zs, m);
    }

    if (e2 == 0) {
        const float inv = (zs > 0.f) ? (1.f / zs) : 1.f;
        float4 o;
        o.x = accV.x * inv; o.y = accV.y * inv;
        o.z = accV.z * inv; o.w = accV.w * inv;
        *(float4*)(out + (size_t)node * 64 + (hq << 2)) = o;
    }
}

extern "C" void kernel_launch(void* const* d_in, const int* in_sizes, int n_in,
                              void* d_out, int out_size, void* d_ws, size_t ws_size,
                              hipStream_t stream) {
    const float* h   = (const float*)d_in[0];
    const float* s_l = (const float*)d_in[1];
    const float* Wq  = (const float*)d_in[2];
    const float* bq  = (const float*)d_in[3];
    const float* Wk  = (const float*)d_in[4];
    const float* bk  = (const float*)d_in[5];
    const float* Wv  = (const float*)d_in[6];
    const float* bv  = (const float*)d_in[7];
    const int*   src = (const int*)d_in[8];
    const int*   dst = (const int*)d_in[9];
    float* out = (float*)d_out;

    const int N = in_sizes[0] / 64;   // 50000
    const int E = in_sizes[8];        // 800000

    // workspace: Q fp32 (N*64) | KV packed (N*64) | cursor (N int) | list int (N*64)
    float*    Q      = (float*)d_ws;
    unsigned* KV     = (unsigned*)(Q + (size_t)N * NODES_DIM);
    int*      cursor = (int*)(KV + (size_t)N * NODES_DIM);
    int*      list   = cursor + N;

    hipMemsetAsync(cursor, 0, (size_t)N * sizeof(int), stream);

    // heterogeneous grid: 2/3 qkv blocks (32 rows each), 1/3 fill blocks
    const int qbc = (N + 31) / 32;            // 1563
    const int fbc = (E + 1023) / 1024;        // 782
    const int g3  = ((qbc + 1) / 2 > fbc) ? (qbc + 1) / 2 : fbc;
    qkv_fill_kernel<<<3 * g3, 256, 0, stream>>>(
        h, Wq, bq, Wk, bk, Wv, bv, Q, KV, N,
        src, dst, cursor, list, E);

    const long long nthreads = (long long)N * 64;
    node_kernel<<<(int)((nthreads + 255) / 256), 256, 0, stream>>>(
        Q, KV, s_l, cursor, list, out, N);
}